// Round 4
// baseline (249.492 us; speedup 1.0000x reference)
//
#include <hip/hip_runtime.h>
#include <hip/hip_bf16.h>
#include <stdint.h>

typedef __hip_bfloat16 bf16;
typedef __attribute__((ext_vector_type(8))) short bf16x8;   // 8 bf16 = 4 VGPRs (MFMA A/B frag)
typedef __attribute__((ext_vector_type(4))) float f32x4;    // 16x16 MFMA C/D frag
typedef __attribute__((ext_vector_type(16))) float f32x16;  // 32x32 MFMA C/D frag
typedef __attribute__((ext_vector_type(4))) unsigned u32x4;

#define B_  2
#define L_  2048
#define D_  1024
#define H_  16
#define HD_ 64
#define BH_ 32
#define L2E 1.4426950408889634f

#define DEV static __device__ __forceinline__

DEV short f2bf(float f) {
    bf16 h = __float2bfloat16(f);
    return __builtin_bit_cast(short, h);
}

DEV unsigned pk2(float lo, float hi) {   // bf16(lo) | bf16(hi)<<16  (compiler fuses to cvt_pk)
    unsigned a = (unsigned short)__builtin_bit_cast(unsigned short, __float2bfloat16(lo));
    unsigned b = (unsigned short)__builtin_bit_cast(unsigned short, __float2bfloat16(hi));
    return a | (b << 16);
}

DEV f32x4 mfma16(bf16x8 a, bf16x8 b, f32x4 c) {
    return __builtin_amdgcn_mfma_f32_16x16x32_bf16(a, b, c, 0, 0, 0);
}
DEV f32x16 mfma32(bf16x8 a, bf16x8 b, f32x16 c) {
    return __builtin_amdgcn_mfma_f32_32x32x16_bf16(a, b, c, 0, 0, 0);
}

// async global->LDS, 16B per lane; lds ptr must be wave-uniform (HW adds lane*16)
DEV void async_ld16(const void* g, void* lds_uniform) {
    __builtin_amdgcn_global_load_lds((const __attribute__((address_space(1))) void*)g,
                                     (__attribute__((address_space(3))) void*)lds_uniform,
                                     16, 0, 0);
}

// XOR-swizzled element offset inside a [rows][64] bf16 tile (128B rows).
DEV int swz(int row, int col) {
    int blk = (row << 3) + (col >> 3);
    blk ^= (row & 7);
    return (blk << 3) + (col & 7);
}

// ---------------------------------------------------------------- cast x -> bf16
__global__ __launch_bounds__(256) void k_cast_x(const float* __restrict__ x,
                                                bf16* __restrict__ xb, int n8) {
    int i = blockIdx.x * 256 + threadIdx.x;
    if (i >= n8) return;
    const float4* src = (const float4*)x + (size_t)i * 2;
    float4 a = src[0], b = src[1];
    bf16x8 v;
    v[0]=f2bf(a.x); v[1]=f2bf(a.y); v[2]=f2bf(a.z); v[3]=f2bf(a.w);
    v[4]=f2bf(b.x); v[5]=f2bf(b.y); v[6]=f2bf(b.z); v[7]=f2bf(b.w);
    *(bf16x8*)(xb + (size_t)i * 8) = v;
}

// ------------------------------------------- cast + transpose weights -> WT[n][k] bf16
__global__ __launch_bounds__(256) void k_cast_wT(const float* __restrict__ W0, const float* __restrict__ W1,
                                                 const float* __restrict__ W2, const float* __restrict__ W3,
                                                 bf16* __restrict__ WT) {
    const float* W = (blockIdx.z == 0) ? W0 : (blockIdx.z == 1) ? W1 : (blockIdx.z == 2) ? W2 : W3;
    __shared__ float tile[64][65];
    const int r0 = blockIdx.y * 64, c0 = blockIdx.x * 64;
    const int tx = threadIdx.x & 63, ty = threadIdx.x >> 6;
    #pragma unroll
    for (int i = 0; i < 16; ++i) {
        int r = ty + i * 4;
        tile[r][tx] = W[(size_t)(r0 + r) * D_ + c0 + tx];
    }
    __syncthreads();
    bf16* out = WT + (size_t)blockIdx.z * D_ * D_;
    #pragma unroll
    for (int i = 0; i < 16; ++i) {
        int n = ty + i * 4;
        out[(size_t)(c0 + n) * D_ + r0 + tx] = __float2bfloat16(tile[tx][n]);
    }
}

// ---------------------------------------------------------------- GEMM 128x128, BK=64
template <int MODE>
__global__ __launch_bounds__(256) void k_gemm(const bf16* __restrict__ A, const bf16* __restrict__ BT,
                                              void* __restrict__ C) {
    __shared__ __align__(16) bf16 As[128 * 64];
    __shared__ __align__(16) bf16 Bs[128 * 64];
    const int t = threadIdx.x;
    const int w = t >> 6, lane = t & 63;
    const int lr = lane & 15, lg = lane >> 4;
    const int wr = (w >> 1) * 64, wc = (w & 1) * 64;
    const size_t am0 = (size_t)blockIdx.y * 128;
    const size_t bn0 = (size_t)blockIdx.x * 128;

    f32x4 acc[4][4] = {};

    for (int kt = 0; kt < 1024 / 64; ++kt) {
        const int k0 = kt * 64;
        if (kt) __syncthreads();
        #pragma unroll
        for (int c = 0; c < 4; ++c) {
            int phys = c * 256 + t;
            int lb = phys ^ ((phys >> 3) & 7);
            int row = lb >> 3, cb = lb & 7;
            int ldsoff = (c * 256 + w * 64) * 8;
            async_ld16(A  + (am0 + row) * 1024 + k0 + cb * 8, (void*)(As + ldsoff));
            async_ld16(BT + (bn0 + row) * 1024 + k0 + cb * 8, (void*)(Bs + ldsoff));
        }
        __syncthreads();
        bf16x8 af[4][2], bfv[4][2];
        #pragma unroll
        for (int mi = 0; mi < 4; ++mi)
            #pragma unroll
            for (int ks = 0; ks < 2; ++ks)
                af[mi][ks] = *(const bf16x8*)(As + swz(wr + mi * 16 + lr, ks * 32 + lg * 8));
        #pragma unroll
        for (int ni = 0; ni < 4; ++ni)
            #pragma unroll
            for (int ks = 0; ks < 2; ++ks)
                bfv[ni][ks] = *(const bf16x8*)(Bs + swz(wc + ni * 16 + lr, ks * 32 + lg * 8));
        #pragma unroll
        for (int mi = 0; mi < 4; ++mi)
            #pragma unroll
            for (int ni = 0; ni < 4; ++ni) {
                acc[mi][ni] = mfma16(af[mi][0], bfv[ni][0], acc[mi][ni]);
                acc[mi][ni] = mfma16(af[mi][1], bfv[ni][1], acc[mi][ni]);
            }
    }

    #pragma unroll
    for (int mi = 0; mi < 4; ++mi)
        #pragma unroll
        for (int ni = 0; ni < 4; ++ni)
            #pragma unroll
            for (int j = 0; j < 4; ++j) {
                size_t gm = am0 + wr + mi * 16 + lg * 4 + j;
                size_t gn = bn0 + wc + ni * 16 + lr;
                float v = acc[mi][ni][j];
                if (MODE == 0) {
                    int which = (int)(gn >> 10);
                    int h = (int)((gn >> 6) & 15);
                    int d = (int)(gn & 63);
                    int bb = (int)(gm >> 11);
                    int l = (int)(gm & 2047);
                    // fold 0.125 * log2(e) into Q so attention works in exp2 domain
                    if (which == 0) v *= 0.18033688011112042f;
                    bf16* dst = (bf16*)C + (size_t)which * ((size_t)BH_ * L_ * HD_);
                    dst[((size_t)(bb * H_ + h) * L_ + l) * HD_ + d] = __float2bfloat16(v);
                } else {
                    ((float*)C)[gm * 1024 + gn] = v;
                }
            }
}

// ---------------------------------------------------------------- V transpose per head
__global__ __launch_bounds__(256) void k_transpose_v(const bf16* __restrict__ Vb, bf16* __restrict__ VTb) {
    __shared__ __align__(16) short tile[64][80];
    const int bh = blockIdx.y;
    const int l0 = blockIdx.x * 64;
    const int t = threadIdx.x;
    const int rr = t >> 2, cc = (t & 3) * 16;
    const short* src = (const short*)(Vb + ((size_t)bh * L_ + l0 + rr) * HD_ + cc);
    *(bf16x8*)&tile[rr][cc]     = *(const bf16x8*)src;
    *(bf16x8*)&tile[rr][cc + 8] = *(const bf16x8*)(src + 8);
    __syncthreads();
    bf16x8 v0, v1;
    #pragma unroll
    for (int i = 0; i < 8; ++i) v0[i] = tile[cc + i][rr];
    #pragma unroll
    for (int i = 0; i < 8; ++i) v1[i] = tile[cc + 8 + i][rr];
    short* dst = (short*)(VTb + ((size_t)bh * HD_ + rr) * L_ + l0 + cc);
    *(bf16x8*)dst       = v0;
    *(bf16x8*)(dst + 8) = v1;
}

// ---------------------------------------------------------------- fused attention (LDS-free loop)
// grid (L/32, H), 128 threads = 2 waves. Each wave: 32 q-rows x its kv-half (1024 kv), both batches.
// S^T = mfma32(K, Q^T) with K rows loaded PERMUTED by pi (blocks 1<->2, 5<->6 of 4):
// lane (lq,lh) then owns S rows for exactly kv {lh*8..+7} u {16+lh*8..+7} -> PV B-frag is a
// direct in-lane pack of p[0..7], p[8..15]. No cross-lane P movement at all.
__global__ __launch_bounds__(128, 2) void k_attn(const bf16* __restrict__ Qb, const bf16* __restrict__ Kb,
                                                 const bf16* __restrict__ VTb, const float* __restrict__ PE,
                                                 bf16* __restrict__ Ob) {
    __shared__ float sh[64][68];   // kv-split merge buffer (epilogue only)
    const int h  = blockIdx.y;
    const int q0 = blockIdx.x * 32;
    const int t  = threadIdx.x;
    const int w  = t >> 6;          // kv-half owner
    const int l  = t & 63;
    const int lq = l & 31;          // this lane's q-row (and row-read index)
    const int lh = l >> 5;          // half selector within wave

    // pi(lq): involution swapping 4-blocks 1<->2 and 5<->6 (A-row m holds K[kv0+pi(m)])
    const int pb = (lq >> 2) & 3;
    const int prow = lq + (pb == 1 ? 4 : (pb == 2 ? -4 : 0));

    // Q B-fragments, hoisted: Qf[bi][dm] = Q[q0+lq][dm*16 + lh*8 .. +8]
    bf16x8 Qf[2][4];
    #pragma unroll
    for (int bi = 0; bi < 2; ++bi)
        #pragma unroll
        for (int dm = 0; dm < 4; ++dm)
            Qf[bi][dm] = *(const bf16x8*)(Qb + ((size_t)(bi * H_ + h) * L_ + q0 + lq) * HD_ + dm * 16 + lh * 8);

    const bf16* kb[2] = { Kb  + (size_t)(0 * H_ + h) * L_ * HD_,
                          Kb  + (size_t)(1 * H_ + h) * L_ * HD_ };
    const bf16* vb[2] = { VTb + (size_t)(0 * H_ + h) * HD_ * L_,
                          VTb + (size_t)(1 * H_ + h) * HD_ * L_ };
    const float* per = PE + ((size_t)h * L_ + q0 + lq) * L_;

    f32x16 o[2][2] = {};                       // [bi][d0-half]  O^T accum
    float mrun[2] = { -3e38f, -3e38f };
    float lpart[2] = { 0.f, 0.f };

    int kv0 = w * 1024;
    // PE gather bases for rows r: kv(r) = pi((r&3)+8*(r>>2)+4*lh); per lane these are four
    // contiguous 4-runs at (g>>1)*16 + (g&1)*4 + lh*8
    int peoff[4];
    #pragma unroll
    for (int g = 0; g < 4; ++g)
        peoff[g] = (g >> 1) * 16 + (g & 1) * 4 + lh * 8;

    float4 pec[4], pen[4];
    #pragma unroll
    for (int g = 0; g < 4; ++g)
        pec[g] = *(const float4*)(per + kv0 + peoff[g]);

    for (int it = 0; it < 32; ++it, kv0 += 32) {
        const int kvn = (it < 31) ? kv0 + 32 : kv0;   // clamp last prefetch in-range
        #pragma unroll
        for (int g = 0; g < 4; ++g)
            pen[g] = *(const float4*)(per + kvn + peoff[g]);

        #pragma unroll
        for (int bi = 0; bi < 2; ++bi) {
            // K A-frags (pi-permuted row): K[kv0+prow][dm*16 + lh*8 ..+8]
            bf16x8 kf[4];
            #pragma unroll
            for (int dm = 0; dm < 4; ++dm)
                kf[dm] = *(const bf16x8*)(kb[bi] + (size_t)(kv0 + prow) * HD_ + dm * 16 + lh * 8);
            // VT A-frags: VT[d0*32+lq][kv0 + m*16 + lh*8 ..+8]
            bf16x8 vf[2][2];
            #pragma unroll
            for (int d0 = 0; d0 < 2; ++d0)
                #pragma unroll
                for (int m = 0; m < 2; ++m)
                    vf[d0][m] = *(const bf16x8*)(vb[bi] + (size_t)(d0 * 32 + lq) * L_ + kv0 + m * 16 + lh * 8);

            // S^T = sum_d K·Q^T   (lane's row r -> kv = pi((r&3)+8*(r>>2)+4*lh))
            f32x16 s = {};
            #pragma unroll
            for (int dm = 0; dm < 4; ++dm)
                s = mfma32(kf[dm], Qf[bi][dm], s);

            // v = s + PE*log2e  (pec[g][j] matches kv(r) with g=r>>2, j=r&3)
            float v[16];
            #pragma unroll
            for (int r = 0; r < 16; ++r)
                v[r] = fmaf(pec[r >> 2][r & 3], L2E, s[r]);

            // row max: in-reg tree + cross-half shuffle (well-defined, direction-free)
            float t0 = fmaxf(fmaxf(v[0], v[1]), fmaxf(v[2], v[3]));
            float t1 = fmaxf(fmaxf(v[4], v[5]), fmaxf(v[6], v[7]));
            float t2 = fmaxf(fmaxf(v[8], v[9]), fmaxf(v[10], v[11]));
            float t3 = fmaxf(fmaxf(v[12], v[13]), fmaxf(v[14], v[15]));
            float vmh = fmaxf(fmaxf(t0, t1), fmaxf(t2, t3));
            float vm = fmaxf(vmh, __shfl_xor(vmh, 32, 64));

            float mold = mrun[bi];
            float mnew = mold;
            if (!__all(vm <= mold + 10.f)) {        // defer-max: skip rescale when growth small
                mnew = fmaxf(mold, vm);
                float scl = __builtin_amdgcn_exp2f(mold - mnew);
                mrun[bi] = mnew;
                lpart[bi] *= scl;
                #pragma unroll
                for (int r = 0; r < 16; ++r) { o[bi][0][r] *= scl; o[bi][1][r] *= scl; }
            }

            float p[16], ssum = 0.f;
            #pragma unroll
            for (int r = 0; r < 16; ++r) {
                p[r] = __builtin_amdgcn_exp2f(v[r] - mnew);
                ssum += p[r];
            }
            lpart[bi] += ssum;

            // PV B-frags: thanks to pi, element i of frag m is this lane's own p[m*8+i]
            unsigned a[8];
            #pragma unroll
            for (int j = 0; j < 8; ++j)
                a[j] = pk2(p[2 * j], p[2 * j + 1]);
            u32x4 w0 = { a[0], a[1], a[2], a[3] };
            u32x4 w1 = { a[4], a[5], a[6], a[7] };
            bf16x8 pf0 = __builtin_bit_cast(bf16x8, w0);
            bf16x8 pf1 = __builtin_bit_cast(bf16x8, w1);

            // O^T += VT · P^T
            o[bi][0] = mfma32(vf[0][0], pf0, o[bi][0]);
            o[bi][0] = mfma32(vf[0][1], pf1, o[bi][0]);
            o[bi][1] = mfma32(vf[1][0], pf0, o[bi][1]);
            o[bi][1] = mfma32(vf[1][1], pf1, o[bi][1]);
        }
        #pragma unroll
        for (int g = 0; g < 4; ++g) pec[g] = pen[g];
    }

    // combine l across the two lane-halves (same q)
    float lsum[2];
    #pragma unroll
    for (int bi = 0; bi < 2; ++bi)
        lsum[bi] = lpart[bi] + __shfl_xor(lpart[bi], 32, 64);

    // kv-split merge: wave1 dumps state, wave0 merges + stores
    if (w == 1) {
        #pragma unroll
        for (int bi = 0; bi < 2; ++bi)
            #pragma unroll
            for (int d0 = 0; d0 < 2; ++d0)
                #pragma unroll
                for (int r = 0; r < 16; ++r)
                    sh[l][bi * 32 + d0 * 16 + r] = o[bi][d0][r];
        sh[l][64] = mrun[0]; sh[l][65] = mrun[1];
        sh[l][66] = lsum[0]; sh[l][67] = lsum[1];
    }
    __syncthreads();
    if (w == 0) {
        #pragma unroll
        for (int bi = 0; bi < 2; ++bi) {
            float m1 = sh[l][64 + bi], l1 = sh[l][66 + bi];
            float ms = fmaxf(mrun[bi], m1);
            float c0 = __builtin_amdgcn_exp2f(mrun[bi] - ms);
            float c1 = __builtin_amdgcn_exp2f(m1 - ms);
            float inv = __builtin_amdgcn_rcpf(lsum[bi] * c0 + l1 * c1);
            #pragma unroll
            for (int d0 = 0; d0 < 2; ++d0)
                #pragma unroll
                for (int r = 0; r < 16; r += 2) {
                    float e0 = (o[bi][d0][r]     * c0 + sh[l][bi * 32 + d0 * 16 + r]     * c1) * inv;
                    float e1 = (o[bi][d0][r + 1] * c0 + sh[l][bi * 32 + d0 * 16 + r + 1] * c1) * inv;
                    int d = d0 * 32 + ((r & 3) + 8 * (r >> 2)) + lh * 4;
                    *(unsigned*)(Ob + ((size_t)bi * L_ + q0 + lq) * D_ + h * HD_ + d) = pk2(e0, e1);
                }
        }
    }
}

// ---------------------------------------------------------------- launch
extern "C" void kernel_launch(void* const* d_in, const int* in_sizes, int n_in,
                              void* d_out, int out_size, void* d_ws, size_t ws_size,
                              hipStream_t stream) {
    const float* x  = (const float*)d_in[0];
    const float* pe = (const float*)d_in[1];
    const float* Wq = (const float*)d_in[2];
    const float* Wk = (const float*)d_in[3];
    const float* Wv = (const float*)d_in[4];
    const float* Wo = (const float*)d_in[5];
    float* out = (float*)d_out;

    const size_t MD = (size_t)4096 * 1024;
    const size_t HS = (size_t)BH_ * L_ * HD_;

    bf16* Xb  = (bf16*)d_ws;        // x in bf16            [4096][1024]
    bf16* WT  = Xb + MD;            // WqT|WkT|WvT|WoT      [4096][1024]
    bf16* Qb  = WT + MD;            // [bh][L][64]  (pre-scaled by 0.125*log2e)
    bf16* Kb  = Qb + HS;
    bf16* Vb  = Kb + HS;
    bf16* VTb = Vb + HS;            // [bh][64][L]
    bf16* Ob  = VTb + HS;           // attention out        [4096][1024]

    k_cast_x<<<2048, 256, 0, stream>>>(x, Xb, 4096 * 1024 / 8);
    k_cast_wT<<<dim3(16, 16, 4), 256, 0, stream>>>(Wq, Wk, Wv, Wo, WT);
    k_gemm<0><<<dim3(24, 32), 256, 0, stream>>>(Xb, WT, (void*)Qb);          // QKV, N=3072
    k_transpose_v<<<dim3(32, 32), 256, 0, stream>>>(Vb, VTb);
    k_attn<<<dim3(64, 16), 128, 0, stream>>>(Qb, Kb, VTb, pe, Ob);
    k_gemm<1><<<dim3(8, 32), 256, 0, stream>>>(Ob, WT + (size_t)3072 * 1024, (void*)out); // out-proj
}